// Round 9
// baseline (483.570 us; speedup 1.0000x reference)
//
#include <hip/hip_runtime.h>

// Problem constants (from reference)
#define B_    64
#define T_    256
#define VG_   1232
#define S_    32
#define LW_   64
#define VW_   8000
#define NTAGS 8
#define NEG_  (-1e30f)
#define LP_STRIDE 34   // per (b,t): [0]=blank lp, [1..32]=gloss lp, [33]=pad
#define LOG2E 1.44269504088896340736f
#define LN2   0.69314718055994530942f
#define NPROD (B_ * T_ / 4)   // 4096 producer blocks (4 rows each)

__device__ __forceinline__ float exp2g(float x) {
    float r; asm("v_exp_f32 %0, %1" : "=v"(r) : "v"(x)); return r;
}
__device__ __forceinline__ float log2g(float x) {
    float r; asm("v_log_f32 %0, %1" : "=v"(r) : "v"(x)); return r;
}
// Whole-wave shift-up-by-1 via DPP WAVE_SHR1 (0x138): lane l gets src[l-1],
// lane 0 keeps `fill`. Pure VALU: no LDS round-trip, no lgkmcnt.
__device__ __forceinline__ float dpp_shr1(float x, float fill) {
    int r = __builtin_amdgcn_update_dpp(
        __builtin_bit_cast(int, fill), __builtin_bit_cast(int, x),
        0x138, 0xF, 0xF, false);
    return __builtin_bit_cast(float, r);
}
// One DPP row_shl<K> add step (ctrl must be a literal constant -> template).
template <int CTRL>
__device__ __forceinline__ float dpp_add(float x) {
    int s = __builtin_amdgcn_update_dpp(
        0, __builtin_bit_cast(int, x), CTRL, 0xF, 0xF, true);
    return x + __builtin_bit_cast(float, s);
}
// Wave sum to lane 0 (lanes 16/32/48 also hold it): DPP row_shl 1/2/4/8 on
// the VALU pipe + two cross-lane combines.
__device__ __forceinline__ float wave_sum_to0(float x) {
    x = dpp_add<0x101>(x);
    x = dpp_add<0x102>(x);
    x = dpp_add<0x104>(x);
    x = dpp_add<0x108>(x);
    x += __shfl_xor(x, 16, 64);
    x += __shfl_xor(x, 32, 64);
    return x;
}

// ---------------------------------------------------------------------------
// Scan body (identical math to R8), specialized on Tlen == T.
// ---------------------------------------------------------------------------
template <bool FULL>
__device__ __forceinline__ void scan_body(
    const float* __restrict__ tile, int lane, int off, bool ok2, int Tlen,
    float& alpha, float& a64)
{
    auto STEP = [&](int t, float lp, float lpB) {
        const float a1 = dpp_shr1(alpha, NEG_);          // lane0 -> NEG
        float a2 = dpp_shr1(a1, NEG_);                   // lanes0,1 -> NEG
        a2 = ok2 ? a2 : NEG_;
        const float m3 = fmaxf(alpha, fmaxf(a1, a2));    // v_max3
        const float e0 = exp2g(alpha - m3);
        const float e1 = exp2g(a1 - m3);
        const float e2 = exp2g(a2 - m3);
        const float nw = (m3 + lp) + log2g((e0 + e1) + e2);
        const float m2 = fmaxf(a64, alpha);              // a63 lane-local on 63
        const float n64 = (m2 + lpB) + log2g(exp2g(a64 - m2) + exp2g(alpha - m2));
        if (FULL || t < Tlen) { alpha = nw; a64 = n64; } // uniform
    };

    float cur[4], curB[4];
#pragma unroll
    for (int j = 0; j < 4; ++j) {
        cur[j]  = tile[(1 + j) * LP_STRIDE + off];
        curB[j] = tile[(1 + j) * LP_STRIDE];
    }
    int tbase = 1;
    for (int g = 0; g < 63; ++g) {
        float nxt[4], nxtB[4];
        const int tb2 = tbase + 4;             // last group reads pad row 256
#pragma unroll
        for (int j = 0; j < 4; ++j) {
            nxt[j]  = tile[(tb2 + j) * LP_STRIDE + off];
            nxtB[j] = tile[(tb2 + j) * LP_STRIDE];
        }
#pragma unroll
        for (int j = 0; j < 4; ++j) STEP(tbase + j, cur[j], curB[j]);
#pragma unroll
        for (int j = 0; j < 4; ++j) { cur[j] = nxt[j]; curB[j] = nxtB[j]; }
        tbase += 4;
    }
#pragma unroll
    for (int j = 0; j < 3; ++j) STEP(253 + j, cur[j], curB[j]);
}

// ---------------------------------------------------------------------------
// Fused kernel.
//   blocks 0..4095 : produce lp rows [blk*4, blk*4+4)  (= R8's kA math).
//                    Batch b is produced by blocks [64b, 64b+63]; each
//                    releases via threadfence + atomicAdd(batch_cnt[b]).
//   block 64b+63   : additionally spin-waits for batch_cnt[b]==64, stages the
//                    256x34 tile to LDS, scans (wave 0), writes loss_ws[b].
//   block 4096     : NLL gather.
//   65 completion arrivals (64 scanners + NLL); last writes out[0..2].
// Counters are zeroed by hipMemsetAsync before launch.
// ---------------------------------------------------------------------------
__global__ __launch_bounds__(256) void k_fused(
    const float* __restrict__ scores, const int* __restrict__ tag_ids,
    const int* __restrict__ glosses, const int* __restrict__ frames_len,
    const int* __restrict__ glosses_len, const int* __restrict__ words,
    const float* __restrict__ words_out,
    int* __restrict__ batch_cnt, int* __restrict__ done_cnt,
    float* __restrict__ loss_ws, float* __restrict__ nll_ws,
    float* __restrict__ lp_ws, float* __restrict__ out)
{
    __shared__ __align__(16) float smem[(T_ + 1) * LP_STRIDE];  // 35 KB union
    __shared__ int   cntL[NTAGS];
    __shared__ float tm2L[4][NTAGS];
    const int tid = threadIdx.x;
    const int blk = blockIdx.x;

    if (blk < NPROD) {
        // ======================= producer =======================
        int* tagL = (int*)smem;                 // first 4928 B of the union
        if (tid < NTAGS) cntL[tid] = 0;

        const int lane = tid & 63;
        const int wv   = tid >> 6;
        const int row  = blk * 4 + wv;          // [0, B*T)
        const int b    = row >> 8;              // row / T_
        const float* srow = scores + (size_t)row * VG_;

        // gather index (early): lane 0 -> blank(0), lanes 1..32 -> glosses
        const int gidx = (lane >= 1 && lane < 33) ? glosses[b * S_ + lane - 1] : 0;

        // long-latency score loads (308 float4/row; 5/lane, last iter 52 lanes)
        float4 sv[5];
#pragma unroll
        for (int i = 0; i < 5; ++i) {
            const int idx = i * 64 + lane;
            const bool act = (i < 4) || (lane < 52);
            sv[i] = act ? ((const float4*)srow)[idx]
                        : make_float4(0.f, 0.f, 0.f, 0.f);
        }

        __syncthreads();   // cntL zeroed before atomics

        // stage tags + per-block tag counts (hidden under the score loads)
#pragma unroll
        for (int i = 0; i < 5; ++i) {
            const int idx = i * 256 + tid;
            if (idx < VG_) {
                const int g = tag_ids[idx];
                tagL[idx] = g;
                atomicAdd(&cntL[g], 1);         // integer: deterministic
            }
        }
        __syncthreads();

        int4 tv[5];
#pragma unroll
        for (int i = 0; i < 5; ++i) {
            const int idx = i * 64 + lane;
            const bool act = (i < 4) || (lane < 52);
            tv[i] = act ? ((const int4*)tagL)[idx] : make_int4(0, 0, 0, 0);
        }
        const float gval = srow[gidx];
        const int   gtag = tagL[gidx];

        // pass 1: per-tag sums
        float sums[NTAGS];
#pragma unroll
        for (int n = 0; n < NTAGS; ++n) sums[n] = 0.f;
#pragma unroll
        for (int i = 0; i < 5; ++i) {
            const float xs[4] = {sv[i].x, sv[i].y, sv[i].z, sv[i].w};
            const int   ts[4] = {tv[i].x, tv[i].y, tv[i].z, tv[i].w};
#pragma unroll
            for (int j = 0; j < 4; ++j) {
#pragma unroll
                for (int n = 0; n < NTAGS; ++n)
                    sums[n] += (ts[j] == n) ? xs[j] : 0.f;
            }
        }
#pragma unroll
        for (int n = 0; n < NTAGS; ++n) sums[n] = wave_sum_to0(sums[n]);

        if (lane == 0) {
#pragma unroll
            for (int n = 0; n < NTAGS; ++n)
                tm2L[wv][n] = (0.1f * LOG2E) * sums[n] *
                              __builtin_amdgcn_rcpf((float)cntL[n]);
        }
        __builtin_amdgcn_sched_barrier(0);  // pin ds_write before ds_reads

        // pass 2: max-free base-2 LSE (safe: sumexp <= ~5e5 in f32)
        float se = 0.f;
#pragma unroll
        for (int i = 0; i < 5; ++i) {
            const float xs[4] = {sv[i].x, sv[i].y, sv[i].z, sv[i].w};
            const int   ts[4] = {tv[i].x, tv[i].y, tv[i].z, tv[i].w};
            const bool act = (i < 4) || (lane < 52);
#pragma unroll
            for (int j = 0; j < 4; ++j) {
                const float e = exp2g(fmaf(xs[j], LOG2E, tm2L[wv][ts[j]]));
                se += act ? e : 0.f;
            }
        }
        se = wave_sum_to0(se);
        const float se0 = __builtin_bit_cast(
            float, __builtin_amdgcn_readfirstlane(__builtin_bit_cast(int, se)));
        const float lse2 = log2g(se0);

        if (lane < 33) {
            const float v = fmaf(gval, LOG2E, tm2L[wv][gtag]) - lse2;
            lp_ws[(size_t)row * LP_STRIDE + lane] = v;
        }

        // release this block's 4 rows (validated fence+atomic pattern)
        __threadfence();
        if (tid == 0) atomicAdd(&batch_cnt[b], 1);

        if ((blk & 63) != 63) return;           // plain producers exit here

        // ======================= scanner (block 64b+63) =======================
        if (tid == 0) {
            while (__hip_atomic_load(&batch_cnt[b], __ATOMIC_RELAXED,
                                     __HIP_MEMORY_SCOPE_AGENT) < 64)
                __builtin_amdgcn_s_sleep(2);
        }
        __syncthreads();
        __threadfence();                        // acquire before tile reads

        float* tile = smem;                     // overwrite union (safe: sync'd)
        {
            const float4* src4 = (const float4*)(lp_ws + (size_t)b * T_ * LP_STRIDE);
            float4* dst4 = (float4*)tile;
            float4 r[9];
#pragma unroll
            for (int i = 0; i < 9; ++i) {
                const int idx = i * 256 + tid;
                if (idx < 2176) r[i] = src4[idx];
            }
#pragma unroll
            for (int i = 0; i < 9; ++i) {
                const int idx = i * 256 + tid;
                if (idx < 2176) dst4[idx] = r[i];
            }
        }
        __syncthreads();

        if (tid < 64) {
            // ext[l]: even -> blank, odd -> glosses[b, l>>1]
            const bool odd  = (lane & 1) != 0;
            const int  sIdx = (lane - 1) >> 1;
            bool ok2 = false;
            if (odd && sIdx >= 1) {
                const int g  = glosses[b * S_ + sIdx];
                const int gp = glosses[b * S_ + sIdx - 1];
                ok2 = (g != gp) && (g != 0);
            }
            const int off = odd ? (1 + sIdx) : 0;

            float alpha = NEG_;
            float a64   = NEG_;                 // state 64; valid on lane 63
            {
                const float lp00 = tile[off];
                if (lane <= 1) alpha = lp00;
            }
            const int Tlen = frames_len[b];
            if (Tlen == T_) scan_body<true >(tile, lane, off, ok2, Tlen, alpha, a64);
            else            scan_body<false>(tile, lane, off, ok2, Tlen, alpha, a64);

            const float a64v = __shfl(a64, 63, 64);
            const int i1 = 2 * glosses_len[b];  // in [2, 64]
            const int i0 = i1 - 1;
            const float A0 = __shfl(alpha, i0, 64);
            const float A1 = (i1 >= 64) ? a64v : __shfl(alpha, i1, 64);
            const float mm = fmaxf(A0, A1);
            float loss = -(mm + log2g(exp2g(A0 - mm) + exp2g(A1 - mm))) * LN2;
            if (loss > 1e29f) loss = 0.f;
            if (lane == 0) loss_ws[b] = loss;
        }
    } else {
        // ======================= NLL block (blk == NPROD) =======================
        float* red = smem;
        float acc = 0.f;
        for (int idx = tid; idx < B_ * (LW_ - 1); idx += 256) {
            const int b = idx / (LW_ - 1);
            const int t = idx - b * (LW_ - 1);
            const int tgt = words[b * LW_ + t + 1];
            if (tgt != 0)
                acc -= words_out[((size_t)b * LW_ + t) * VW_ + tgt];
        }
        red[tid] = acc;
        __syncthreads();
        for (int s = 128; s > 0; s >>= 1) {
            if (tid < s) red[tid] += red[tid + s];
            __syncthreads();
        }
        if (tid == 0) nll_ws[0] = red[0];
    }

    // ---- completion: 64 scanners + NLL = 65 arrivals; last writes out ----
    __threadfence();
    int old = 0;
    if (tid == 0) old = atomicAdd(done_cnt, 1);
    if (tid < 64) {
        old = __shfl(old, 0, 64);
        if (old == B_) {                        // 65th arrival
            __threadfence();
            float v = loss_ws[tid];
#pragma unroll
            for (int o = 32; o >= 1; o >>= 1) v += __shfl_xor(v, o, 64);
            if (tid == 0) {
                const float trans = nll_ws[0];
                out[0] = v + trans;             // GLOSS_W = WORD_W = 1
                out[1] = v;
                out[2] = trans;
            }
        }
    }
}

// ---------------------------------------------------------------------------
extern "C" void kernel_launch(void* const* d_in, const int* in_sizes, int n_in,
                              void* d_out, int out_size, void* d_ws, size_t ws_size,
                              hipStream_t stream) {
    const int*   glosses     = (const int*)d_in[0];
    const int*   words       = (const int*)d_in[1];
    const float* scores      = (const float*)d_in[2];
    const float* words_out   = (const float*)d_in[3];
    const int*   frames_len  = (const int*)d_in[4];
    const int*   glosses_len = (const int*)d_in[5];
    const int*   tag_ids     = (const int*)d_in[6];
    float* out = (float*)d_out;

    // ws layout (floats): [0..63] batch_cnt (ints), [64] done_cnt (int),
    // [96..159] loss_ws, [160] nll_ws, [192..] lp_ws (16B-aligned).
    float* w         = (float*)d_ws;
    int*   batch_cnt = (int*)d_ws;
    int*   done_cnt  = batch_cnt + 64;
    float* loss_ws   = w + 96;
    float* nll_ws    = w + 160;
    float* lp_ws     = w + 192;     // B*T*34 floats = 2.23 MB

    hipMemsetAsync(d_ws, 0, 384, stream);   // zero batch_cnt[64] + done_cnt
    k_fused<<<NPROD + 1, 256, 0, stream>>>(
        scores, tag_ids, glosses, frames_len, glosses_len, words, words_out,
        batch_cnt, done_cnt, loss_ws, nll_ws, lp_ws, out);
}

// Round 10
// 101.201 us; speedup vs baseline: 4.7783x; 4.7783x over previous
//
#include <hip/hip_runtime.h>

// Problem constants (from reference)
#define B_    64
#define T_    256
#define VG_   1232
#define S_    32
#define LW_   64
#define VW_   8000
#define NTAGS 8
#define NEG_  (-1e30f)
#define LP_STRIDE 34   // per (b,t): [0]=blank lp, [1..32]=gloss lp, [33]=pad
#define LOG2E 1.44269504088896340736f
#define LN2   0.69314718055994530942f
#define NPROD (B_ * T_ / 4)   // 4096 producer blocks (4 rows each)

__device__ __forceinline__ float exp2g(float x) {
    float r; asm("v_exp_f32 %0, %1" : "=v"(r) : "v"(x)); return r;
}
__device__ __forceinline__ float log2g(float x) {
    float r; asm("v_log_f32 %0, %1" : "=v"(r) : "v"(x)); return r;
}
// Agent-scope (cross-XCD) data movement WITHOUT cache-maintenance fences:
// relaxed agent atomics compile to sc1 ops (write-through / L2-bypass).
__device__ __forceinline__ void st_agent(float* p, float v) {
    __hip_atomic_store(p, v, __ATOMIC_RELAXED, __HIP_MEMORY_SCOPE_AGENT);
}
__device__ __forceinline__ float ld_agent(const float* p) {
    return __hip_atomic_load(p, __ATOMIC_RELAXED, __HIP_MEMORY_SCOPE_AGENT);
}
// Whole-wave shift-up-by-1 via DPP WAVE_SHR1 (0x138): lane l gets src[l-1],
// lane 0 keeps `fill`. Pure VALU: no LDS round-trip, no lgkmcnt.
__device__ __forceinline__ float dpp_shr1(float x, float fill) {
    int r = __builtin_amdgcn_update_dpp(
        __builtin_bit_cast(int, fill), __builtin_bit_cast(int, x),
        0x138, 0xF, 0xF, false);
    return __builtin_bit_cast(float, r);
}
template <int CTRL>
__device__ __forceinline__ float dpp_add(float x) {
    int s = __builtin_amdgcn_update_dpp(
        0, __builtin_bit_cast(int, x), CTRL, 0xF, 0xF, true);
    return x + __builtin_bit_cast(float, s);
}
// Wave sum to lane 0 (lanes 16/32/48 also hold it): DPP row_shl 1/2/4/8 on
// the VALU pipe + two cross-lane combines.
__device__ __forceinline__ float wave_sum_to0(float x) {
    x = dpp_add<0x101>(x);
    x = dpp_add<0x102>(x);
    x = dpp_add<0x104>(x);
    x = dpp_add<0x108>(x);
    x += __shfl_xor(x, 16, 64);
    x += __shfl_xor(x, 32, 64);
    return x;
}

// ---------------------------------------------------------------------------
// Scan body (identical math to R8), specialized on Tlen == T.
// ---------------------------------------------------------------------------
template <bool FULL>
__device__ __forceinline__ void scan_body(
    const float* __restrict__ tile, int lane, int off, bool ok2, int Tlen,
    float& alpha, float& a64)
{
    auto STEP = [&](int t, float lp, float lpB) {
        const float a1 = dpp_shr1(alpha, NEG_);          // lane0 -> NEG
        float a2 = dpp_shr1(a1, NEG_);                   // lanes0,1 -> NEG
        a2 = ok2 ? a2 : NEG_;
        const float m3 = fmaxf(alpha, fmaxf(a1, a2));    // v_max3
        const float e0 = exp2g(alpha - m3);
        const float e1 = exp2g(a1 - m3);
        const float e2 = exp2g(a2 - m3);
        const float nw = (m3 + lp) + log2g((e0 + e1) + e2);
        const float m2 = fmaxf(a64, alpha);              // a63 lane-local on 63
        const float n64 = (m2 + lpB) + log2g(exp2g(a64 - m2) + exp2g(alpha - m2));
        if (FULL || t < Tlen) { alpha = nw; a64 = n64; } // uniform
    };

    float cur[4], curB[4];
#pragma unroll
    for (int j = 0; j < 4; ++j) {
        cur[j]  = tile[(1 + j) * LP_STRIDE + off];
        curB[j] = tile[(1 + j) * LP_STRIDE];
    }
    int tbase = 1;
    for (int g = 0; g < 63; ++g) {
        float nxt[4], nxtB[4];
        const int tb2 = tbase + 4;             // last group reads pad row 256
#pragma unroll
        for (int j = 0; j < 4; ++j) {
            nxt[j]  = tile[(tb2 + j) * LP_STRIDE + off];
            nxtB[j] = tile[(tb2 + j) * LP_STRIDE];
        }
#pragma unroll
        for (int j = 0; j < 4; ++j) STEP(tbase + j, cur[j], curB[j]);
#pragma unroll
        for (int j = 0; j < 4; ++j) { cur[j] = nxt[j]; curB[j] = nxtB[j]; }
        tbase += 4;
    }
#pragma unroll
    for (int j = 0; j < 3; ++j) STEP(253 + j, cur[j], curB[j]);
}

// ---------------------------------------------------------------------------
// Fused kernel, fence-free.
//   blocks 0..4095 : produce 4 lp rows (R8 kA math); lp written via sc1
//                    agent stores; release = vmcnt(0) + syncthreads + plain
//                    atomicAdd(batch_cnt[b]). The 64th arriver of each batch
//                    immediately stages the tile (sc1 agent loads) and scans.
//   block 4096     : NLL gather.
//   done_cnt: 64 scan-executors + NLL = 65 arrivals; last reduces + writes out.
// NO __threadfence anywhere (wbl2/inv storms were R4-R9's hidden cost).
// ---------------------------------------------------------------------------
__global__ __launch_bounds__(256) void k_fused(
    const float* __restrict__ scores, const int* __restrict__ tag_ids,
    const int* __restrict__ glosses, const int* __restrict__ frames_len,
    const int* __restrict__ glosses_len, const int* __restrict__ words,
    const float* __restrict__ words_out,
    int* __restrict__ batch_cnt, int* __restrict__ done_cnt,
    float* __restrict__ loss_ws, float* __restrict__ nll_ws,
    float* __restrict__ lp_ws, float* __restrict__ out)
{
    __shared__ __align__(16) float smem[(T_ + 1) * LP_STRIDE];  // 35 KB union
    __shared__ int   cntL[NTAGS];
    __shared__ float tm2L[4][NTAGS];
    __shared__ int   flagS;
    const int tid  = threadIdx.x;
    const int blk  = blockIdx.x;
    const int lane = tid & 63;

    if (blk < NPROD) {
        // ======================= producer =======================
        int* tagL = (int*)smem;
        if (tid < NTAGS) cntL[tid] = 0;

        const int wv  = tid >> 6;
        const int row = blk * 4 + wv;           // [0, B*T)
        const int b   = blk >> 6;               // 64 blocks per batch
        const float* srow = scores + (size_t)row * VG_;

        const int gidx = (lane >= 1 && lane < 33) ? glosses[b * S_ + lane - 1] : 0;

        float4 sv[5];
#pragma unroll
        for (int i = 0; i < 5; ++i) {
            const int idx = i * 64 + lane;
            const bool act = (i < 4) || (lane < 52);
            sv[i] = act ? ((const float4*)srow)[idx]
                        : make_float4(0.f, 0.f, 0.f, 0.f);
        }

        __syncthreads();   // cntL zeroed before atomics

#pragma unroll
        for (int i = 0; i < 5; ++i) {
            const int idx = i * 256 + tid;
            if (idx < VG_) {
                const int g = tag_ids[idx];
                tagL[idx] = g;
                atomicAdd(&cntL[g], 1);         // integer: deterministic
            }
        }
        __syncthreads();

        int4 tv[5];
#pragma unroll
        for (int i = 0; i < 5; ++i) {
            const int idx = i * 64 + lane;
            const bool act = (i < 4) || (lane < 52);
            tv[i] = act ? ((const int4*)tagL)[idx] : make_int4(0, 0, 0, 0);
        }
        const float gval = srow[gidx];
        const int   gtag = tagL[gidx];

        // pass 1: per-tag sums
        float sums[NTAGS];
#pragma unroll
        for (int n = 0; n < NTAGS; ++n) sums[n] = 0.f;
#pragma unroll
        for (int i = 0; i < 5; ++i) {
            const float xs[4] = {sv[i].x, sv[i].y, sv[i].z, sv[i].w};
            const int   ts[4] = {tv[i].x, tv[i].y, tv[i].z, tv[i].w};
#pragma unroll
            for (int j = 0; j < 4; ++j) {
#pragma unroll
                for (int n = 0; n < NTAGS; ++n)
                    sums[n] += (ts[j] == n) ? xs[j] : 0.f;
            }
        }
#pragma unroll
        for (int n = 0; n < NTAGS; ++n) sums[n] = wave_sum_to0(sums[n]);

        if (lane == 0) {
#pragma unroll
            for (int n = 0; n < NTAGS; ++n)
                tm2L[wv][n] = (0.1f * LOG2E) * sums[n] *
                              __builtin_amdgcn_rcpf((float)cntL[n]);
        }
        __builtin_amdgcn_sched_barrier(0);

        // pass 2: max-free base-2 LSE (safe: sumexp <= ~5e5 in f32)
        float se = 0.f;
#pragma unroll
        for (int i = 0; i < 5; ++i) {
            const float xs[4] = {sv[i].x, sv[i].y, sv[i].z, sv[i].w};
            const int   ts[4] = {tv[i].x, tv[i].y, tv[i].z, tv[i].w};
            const bool act = (i < 4) || (lane < 52);
#pragma unroll
            for (int j = 0; j < 4; ++j) {
                const float e = exp2g(fmaf(xs[j], LOG2E, tm2L[wv][ts[j]]));
                se += act ? e : 0.f;
            }
        }
        se = wave_sum_to0(se);
        const float se0 = __builtin_bit_cast(
            float, __builtin_amdgcn_readfirstlane(__builtin_bit_cast(int, se)));
        const float lse2 = log2g(se0);

        if (lane < 33) {
            const float v = fmaf(gval, LOG2E, tm2L[wv][gtag]) - lse2;
            st_agent(&lp_ws[(size_t)row * LP_STRIDE + lane], v);  // sc1
        }

        // release: drain sc1 stores, then plain device-scope RMW (proven
        // cross-XCD in R5-R8). 64th arriver executes the scan.
        asm volatile("s_waitcnt vmcnt(0)" ::: "memory");
        __syncthreads();
        if (tid == 0) flagS = (atomicAdd(&batch_cnt[b], 1) == 63);
        __syncthreads();
        if (!flagS) return;                      // 63/64 blocks exit here

        // ================== scan (last producer of batch b) ==================
        float* tile = smem;
        {
            const float* lp0 = lp_ws + (size_t)b * T_ * LP_STRIDE;
#pragma unroll
            for (int i = 0; i < 34; ++i)         // 8704 floats, sc1 loads
                tile[i * 256 + tid] = ld_agent(lp0 + i * 256 + tid);
        }
        __syncthreads();

        if (tid < 64) {
            const bool odd  = (lane & 1) != 0;
            const int  sIdx = (lane - 1) >> 1;
            bool ok2 = false;
            if (odd && sIdx >= 1) {
                const int g  = glosses[b * S_ + sIdx];
                const int gp = glosses[b * S_ + sIdx - 1];
                ok2 = (g != gp) && (g != 0);
            }
            const int off = odd ? (1 + sIdx) : 0;

            float alpha = NEG_;
            float a64   = NEG_;                  // state 64; valid on lane 63
            {
                const float lp00 = tile[off];
                if (lane <= 1) alpha = lp00;
            }
            const int Tlen = frames_len[b];
            if (Tlen == T_) scan_body<true >(tile, lane, off, ok2, Tlen, alpha, a64);
            else            scan_body<false>(tile, lane, off, ok2, Tlen, alpha, a64);

            const float a64v = __shfl(a64, 63, 64);
            const int i1 = 2 * glosses_len[b];   // in [2, 64]
            const int i0 = i1 - 1;
            const float A0 = __shfl(alpha, i0, 64);
            const float A1 = (i1 >= 64) ? a64v : __shfl(alpha, i1, 64);
            const float mm = fmaxf(A0, A1);
            float loss = -(mm + log2g(exp2g(A0 - mm) + exp2g(A1 - mm))) * LN2;
            if (loss > 1e29f) loss = 0.f;
            if (lane == 0) st_agent(&loss_ws[b], loss);   // sc1
        }
    } else {
        // ======================= NLL block (blk == NPROD) =======================
        float* red = smem;
        float acc = 0.f;
        for (int idx = tid; idx < B_ * (LW_ - 1); idx += 256) {
            const int b = idx / (LW_ - 1);
            const int t = idx - b * (LW_ - 1);
            const int tgt = words[b * LW_ + t + 1];
            if (tgt != 0)
                acc -= words_out[((size_t)b * LW_ + t) * VW_ + tgt];
        }
        red[tid] = acc;
        __syncthreads();
        for (int s = 128; s > 0; s >>= 1) {
            if (tid < s) red[tid] += red[tid + s];
            __syncthreads();
        }
        if (tid == 0) st_agent(nll_ws, red[0]);          // sc1
    }

    // ---- completion: 64 scan-executors + NLL = 65 arrivals ----
    asm volatile("s_waitcnt vmcnt(0)" ::: "memory");
    __syncthreads();
    int old = 0;
    if (tid == 0) old = atomicAdd(done_cnt, 1);
    if (tid < 64) {
        old = __shfl(old, 0, 64);
        if (old == B_) {                          // 65th arrival
            float v = ld_agent(&loss_ws[tid]);    // sc1
#pragma unroll
            for (int o = 32; o >= 1; o >>= 1) v += __shfl_xor(v, o, 64);
            if (tid == 0) {
                const float trans = ld_agent(nll_ws);
                out[0] = v + trans;               // GLOSS_W = WORD_W = 1
                out[1] = v;
                out[2] = trans;
            }
        }
    }
}

// ---------------------------------------------------------------------------
extern "C" void kernel_launch(void* const* d_in, const int* in_sizes, int n_in,
                              void* d_out, int out_size, void* d_ws, size_t ws_size,
                              hipStream_t stream) {
    const int*   glosses     = (const int*)d_in[0];
    const int*   words       = (const int*)d_in[1];
    const float* scores      = (const float*)d_in[2];
    const float* words_out   = (const float*)d_in[3];
    const int*   frames_len  = (const int*)d_in[4];
    const int*   glosses_len = (const int*)d_in[5];
    const int*   tag_ids     = (const int*)d_in[6];
    float* out = (float*)d_out;

    // ws layout (floats): [0..63] batch_cnt (ints), [64] done_cnt (int),
    // [96..159] loss_ws, [160] nll_ws, [192..] lp_ws (16B-aligned).
    float* w         = (float*)d_ws;
    int*   batch_cnt = (int*)d_ws;
    int*   done_cnt  = batch_cnt + 64;
    float* loss_ws   = w + 96;
    float* nll_ws    = w + 160;
    float* lp_ws     = w + 192;     // B*T*34 floats = 2.23 MB

    hipMemsetAsync(d_ws, 0, 384, stream);   // zero batch_cnt[64] + done_cnt
    k_fused<<<NPROD + 1, 256, 0, stream>>>(
        scores, tag_ids, glosses, frames_len, glosses_len, words, words_out,
        batch_cnt, done_cnt, loss_ws, nll_ws, lp_ws, out);
}

// Round 11
// 52.838 us; speedup vs baseline: 9.1519x; 1.9153x over previous
//
#include <hip/hip_runtime.h>

// Problem constants (from reference)
#define B_    64
#define T_    256
#define VG_   1232
#define S_    32
#define LW_   64
#define VW_   8000
#define NTAGS 8
#define NEG_  (-1e30f)
#define LP_STRIDE 34   // per (b,t): [0]=blank lp, [1..32]=gloss lp, [33]=pad
#define LOG2E 1.44269504088896340736f
#define LN2   0.69314718055994530942f

__device__ __forceinline__ float exp2g(float x) {
    float r; asm("v_exp_f32 %0, %1" : "=v"(r) : "v"(x)); return r;
}
__device__ __forceinline__ float log2g(float x) {
    float r; asm("v_log_f32 %0, %1" : "=v"(r) : "v"(x)); return r;
}
// Agent-scope data movement WITHOUT cache-maintenance fences (sc1 ops go
// through the MALL coherence point; validated R9/R10: absmax 0).
__device__ __forceinline__ void st_agent(float* p, float v) {
    __hip_atomic_store(p, v, __ATOMIC_RELAXED, __HIP_MEMORY_SCOPE_AGENT);
}
__device__ __forceinline__ float ld_agent(const float* p) {
    return __hip_atomic_load(p, __ATOMIC_RELAXED, __HIP_MEMORY_SCOPE_AGENT);
}
// Whole-wave shift-up-by-1 via DPP WAVE_SHR1 (0x138): lane l gets src[l-1],
// lane 0 keeps `fill`. Pure VALU: no LDS round-trip, no lgkmcnt.
__device__ __forceinline__ float dpp_shr1(float x, float fill) {
    int r = __builtin_amdgcn_update_dpp(
        __builtin_bit_cast(int, fill), __builtin_bit_cast(int, x),
        0x138, 0xF, 0xF, false);
    return __builtin_bit_cast(float, r);
}
// One DPP row_shl<K> add step (ctrl must be a literal constant -> template).
template <int CTRL>
__device__ __forceinline__ float dpp_add(float x) {
    int s = __builtin_amdgcn_update_dpp(
        0, __builtin_bit_cast(int, x), CTRL, 0xF, 0xF, true);
    return x + __builtin_bit_cast(float, s);
}
// Wave sum to lane 0 (lanes 16/32/48 also hold it): DPP row_shl 1/2/4/8 on
// the VALU pipe + two cross-lane combines.
__device__ __forceinline__ float wave_sum_to0(float x) {
    x = dpp_add<0x101>(x);
    x = dpp_add<0x102>(x);
    x = dpp_add<0x104>(x);
    x = dpp_add<0x108>(x);
    x += __shfl_xor(x, 16, 64);
    x += __shfl_xor(x, 32, 64);
    return x;
}

// ---------------------------------------------------------------------------
// kA: booster + max-free base-2 logsumexp + gather lp at {blank, glosses}.
// One wave per (b,t) row; 4 waves/block. Per-tag counts via LDS int atomics
// (hidden under in-flight score loads). Block 0 zeroes kB's counter.
// Max-free LSE is safe: scores ~ N(0,1) (+0.1*tag_mean), sumexp <= ~5e5.
// lp stored in LOG2 domain for kB's scan. (Unchanged from R8.)
// ---------------------------------------------------------------------------
__global__ __launch_bounds__(256) void kA_booster(
    const float* __restrict__ scores, const int* __restrict__ tag_ids,
    const int* __restrict__ glosses, float* __restrict__ lp_ws,
    int* __restrict__ counter)
{
    __shared__ __align__(16) int tagL[VG_];
    __shared__ int   cntL[NTAGS];
    __shared__ float tm2L[4][NTAGS];   // TAG_FACTOR * tag_mean * LOG2E
    const int tid = threadIdx.x;

    if (blockIdx.x == 0 && tid == 0) *counter = 0;   // for kB (stream-ordered)
    if (tid < NTAGS) cntL[tid] = 0;

    const int lane = tid & 63;
    const int wv   = tid >> 6;
    const int row  = blockIdx.x * 4 + wv;      // [0, B*T)
    const int b    = row >> 8;                 // row / T_
    const float* srow = scores + (size_t)row * VG_;

    // Gather index (tiny load, issued early): lane 0 -> blank(0),
    // lanes 1..32 -> glosses[b, lane-1].
    const int gidx = (lane >= 1 && lane < 33) ? glosses[b * S_ + lane - 1] : 0;

    // Long-latency score loads (1232 f32 = 308 float4/row; 5/lane, last iter
    // 52 lanes active).
    float4 sv[5];
#pragma unroll
    for (int i = 0; i < 5; ++i) {
        const int idx = i * 64 + lane;
        const bool act = (i < 4) || (lane < 52);
        sv[i] = act ? ((const float4*)srow)[idx] : make_float4(0.f, 0.f, 0.f, 0.f);
    }

    __syncthreads();   // cntL zeroed before atomics below

    // Stage tags + per-block tag counts (hidden under the score loads).
#pragma unroll
    for (int i = 0; i < 5; ++i) {
        const int idx = i * 256 + tid;
        if (idx < VG_) {
            const int g = tag_ids[idx];
            tagL[idx] = g;
            atomicAdd(&cntL[g], 1);            // integer: deterministic
        }
    }
    __syncthreads();

    int4 tv[5];
#pragma unroll
    for (int i = 0; i < 5; ++i) {
        const int idx = i * 64 + lane;
        const bool act = (i < 4) || (lane < 52);
        tv[i] = act ? ((const int4*)tagL)[idx] : make_int4(0, 0, 0, 0);
    }
    // Pre-issue gather loads (overlap pass-1 compute).
    const float gval = srow[gidx];
    const int   gtag = tagL[gidx];

    // Pass 1: per-tag sums (inactive elements contribute 0 to tag 0: harmless)
    float sums[NTAGS];
#pragma unroll
    for (int n = 0; n < NTAGS; ++n) sums[n] = 0.f;
#pragma unroll
    for (int i = 0; i < 5; ++i) {
        const float xs[4] = {sv[i].x, sv[i].y, sv[i].z, sv[i].w};
        const int   ts[4] = {tv[i].x, tv[i].y, tv[i].z, tv[i].w};
#pragma unroll
        for (int j = 0; j < 4; ++j) {
#pragma unroll
            for (int n = 0; n < NTAGS; ++n)
                sums[n] += (ts[j] == n) ? xs[j] : 0.f;
        }
    }
#pragma unroll
    for (int n = 0; n < NTAGS; ++n) sums[n] = wave_sum_to0(sums[n]);

    // Lane 0 publishes tm2 (wave-private LDS row; wave-internal DS ordering)
    if (lane == 0) {
#pragma unroll
        for (int n = 0; n < NTAGS; ++n)
            tm2L[wv][n] = (0.1f * LOG2E) * sums[n] *
                          __builtin_amdgcn_rcpf((float)cntL[n]);
    }
    __builtin_amdgcn_sched_barrier(0);  // pin ds_write before the ds_reads

    // Pass 2: se = sum exp2(x*LOG2E + tm2[tag])  (max-free; no bo[] array)
    float se = 0.f;
#pragma unroll
    for (int i = 0; i < 5; ++i) {
        const float xs[4] = {sv[i].x, sv[i].y, sv[i].z, sv[i].w};
        const int   ts[4] = {tv[i].x, tv[i].y, tv[i].z, tv[i].w};
        const bool act = (i < 4) || (lane < 52);
#pragma unroll
        for (int j = 0; j < 4; ++j) {
            const float e = exp2g(fmaf(xs[j], LOG2E, tm2L[wv][ts[j]]));
            se += act ? e : 0.f;
        }
    }
    se = wave_sum_to0(se);
    const float se0 = __builtin_bit_cast(
        float, __builtin_amdgcn_readfirstlane(__builtin_bit_cast(int, se)));
    const float lse2 = log2g(se0);             // log2(sum e^x)

    // lp2 = (x + tm - lse_nat) * LOG2E = x*LOG2E + tm2 - lse2. Store log2.
    if (lane < 33) {
        const float v = fmaf(gval, LOG2E, tm2L[wv][gtag]) - lse2;
        lp_ws[(size_t)row * LP_STRIDE + lane] = v;
    }
}

// ---------------------------------------------------------------------------
// kB scan body, specialized on whether every step commits (Tlen == T).
// Neighbor exchange via DPP wave_shr1 (VALU) instead of ds_bpermute.
// ---------------------------------------------------------------------------
template <bool FULL>
__device__ __forceinline__ void scan_body(
    const float* __restrict__ tile, int lane, int off, bool ok2, int Tlen,
    float& alpha, float& a64)
{
    auto STEP = [&](int t, float lp, float lpB) {
        const float a1 = dpp_shr1(alpha, NEG_);          // lane0 -> NEG
        float a2 = dpp_shr1(a1, NEG_);                   // lanes0,1 -> NEG
        a2 = ok2 ? a2 : NEG_;
        const float m3 = fmaxf(alpha, fmaxf(a1, a2));    // v_max3
        const float e0 = exp2g(alpha - m3);
        const float e1 = exp2g(a1 - m3);
        const float e2 = exp2g(a2 - m3);
        const float nw = (m3 + lp) + log2g((e0 + e1) + e2);
        const float m2 = fmaxf(a64, alpha);              // a63 lane-local on 63
        const float n64 = (m2 + lpB) + log2g(exp2g(a64 - m2) + exp2g(alpha - m2));
        if (FULL || t < Tlen) { alpha = nw; a64 = n64; } // uniform
    };

    // 255 steps (t=1..255): 63 groups of 4 + tail of 3; next group's 8 LDS
    // reads issued one group ahead (ds latency hidden under the VALU chain).
    float cur[4], curB[4];
#pragma unroll
    for (int j = 0; j < 4; ++j) {
        cur[j]  = tile[(1 + j) * LP_STRIDE + off];
        curB[j] = tile[(1 + j) * LP_STRIDE];
    }
    int tbase = 1;
    for (int g = 0; g < 63; ++g) {
        float nxt[4], nxtB[4];
        const int tb2 = tbase + 4;             // last group reads pad row 256
#pragma unroll
        for (int j = 0; j < 4; ++j) {
            nxt[j]  = tile[(tb2 + j) * LP_STRIDE + off];
            nxtB[j] = tile[(tb2 + j) * LP_STRIDE];
        }
#pragma unroll
        for (int j = 0; j < 4; ++j) STEP(tbase + j, cur[j], curB[j]);
#pragma unroll
        for (int j = 0; j < 4; ++j) { cur[j] = nxt[j]; curB[j] = nxtB[j]; }
        tbase += 4;
    }
#pragma unroll
    for (int j = 0; j < 3; ++j) STEP(253 + j, cur[j], curB[j]);
}

// ---------------------------------------------------------------------------
// kB: blocks 0..63 = CTC alpha scan (lp tile staged to LDS, wave-0 scan).
// Block 64 = NLL gather. Completion is FENCE-FREE: loss/nll go out via sc1
// agent stores, each block drains vmcnt then does one device-scope atomicAdd;
// the 65th arrival reduces via sc1 loads. No __threadfence in this program.
// ---------------------------------------------------------------------------
__global__ __launch_bounds__(256) void kB_ctc_nll_final(
    const float* __restrict__ lp_ws, const int* __restrict__ glosses,
    const int* __restrict__ frames_len, const int* __restrict__ glosses_len,
    const int* __restrict__ words, const float* __restrict__ words_out,
    float* __restrict__ loss_ws, float* __restrict__ nll_ws,
    int* __restrict__ counter, float* __restrict__ out)
{
    __shared__ __align__(16) float tile[(T_ + 1) * LP_STRIDE];  // +pad row
    __shared__ float red[256];
    const int tid = threadIdx.x;

    if (blockIdx.x == B_) {
        // ---- NLL gather: 4032 scattered reads, fixed-order tree reduce ----
        float acc = 0.f;
        for (int idx = tid; idx < B_ * (LW_ - 1); idx += 256) {
            const int b = idx / (LW_ - 1);
            const int t = idx - b * (LW_ - 1);
            const int tgt = words[b * LW_ + t + 1];
            if (tgt != 0)
                acc -= words_out[((size_t)b * LW_ + t) * VW_ + tgt];
        }
        red[tid] = acc;
        __syncthreads();
        for (int s = 128; s > 0; s >>= 1) {
            if (tid < s) red[tid] += red[tid + s];
            __syncthreads();
        }
        if (tid == 0) st_agent(nll_ws, red[0]);          // sc1
    } else {
        const int b = blockIdx.x;
        // ---- stage lp tile: 8704 floats = 2176 float4, 256 threads ----
        // (plain loads: kA->kB coherence comes from the kernel boundary)
        {
            const float4* src4 = (const float4*)(lp_ws + (size_t)b * T_ * LP_STRIDE);
            float4* dst4 = (float4*)tile;
            float4 r[9];
#pragma unroll
            for (int i = 0; i < 9; ++i) {
                const int idx = i * 256 + tid;
                if (idx < 2176) r[i] = src4[idx];
            }
#pragma unroll
            for (int i = 0; i < 9; ++i) {
                const int idx = i * 256 + tid;
                if (idx < 2176) dst4[idx] = r[i];
            }
        }
        __syncthreads();
        if (tid >= 64) return;                 // scan is single-wave
        const int lane = tid;

        // ext[l]: even -> blank, odd -> glosses[b, l>>1]
        const bool odd  = (lane & 1) != 0;
        const int  sIdx = (lane - 1) >> 1;     // valid when odd
        bool ok2 = false;                      // may take the l-2 skip path
        if (odd && sIdx >= 1) {
            const int g  = glosses[b * S_ + sIdx];
            const int gp = glosses[b * S_ + sIdx - 1];
            ok2 = (g != gp) && (g != 0);
        }
        const int off = odd ? (1 + sIdx) : 0;  // column in the 34-wide row

        float alpha = NEG_;
        float a64   = NEG_;                    // state 64; valid on lane 63
        {
            const float lp00 = tile[off];
            if (lane <= 1) alpha = lp00;       // alpha0[0], alpha0[1]
        }
        const int Tlen = frames_len[b];

        if (Tlen == T_) scan_body<true >(tile, lane, off, ok2, Tlen, alpha, a64);
        else            scan_body<false>(tile, lane, off, ok2, Tlen, alpha, a64);

        const float a64v = __shfl(a64, 63, 64);
        const int i1 = 2 * glosses_len[b];     // in [2, 64]
        const int i0 = i1 - 1;
        const float A0 = __shfl(alpha, i0, 64);
        const float A1 = (i1 >= 64) ? a64v : __shfl(alpha, i1, 64);
        const float mm = fmaxf(A0, A1);
        float loss = -(mm + log2g(exp2g(A0 - mm) + exp2g(A1 - mm))) * LN2;
        if (loss > 1e29f) loss = 0.f;
        if (lane == 0) st_agent(&loss_ws[b], loss);      // sc1
    }

    // ---- completion, fence-free: drain own sc1 store, one RMW each.
    // (scan blocks: only wave 0 reaches here; NLL block: all waves, but only
    //  tid 0 did the store and only tid 0 does the RMW.)
    asm volatile("s_waitcnt vmcnt(0)" ::: "memory");
    int old = 0;
    if (tid == 0) old = atomicAdd(counter, 1);
    if (tid < 64) {
        old = __shfl(old, 0, 64);
        if (old == B_) {                       // 65th arrival
            float v = ld_agent(&loss_ws[tid]); // sc1: reads MALL-coherent data
#pragma unroll
            for (int o = 32; o >= 1; o >>= 1) v += __shfl_xor(v, o, 64);
            if (tid == 0) {
                const float trans = ld_agent(nll_ws);
                out[0] = v + trans;            // GLOSS_W = WORD_W = 1
                out[1] = v;
                out[2] = trans;
            }
        }
    }
}

// ---------------------------------------------------------------------------
extern "C" void kernel_launch(void* const* d_in, const int* in_sizes, int n_in,
                              void* d_out, int out_size, void* d_ws, size_t ws_size,
                              hipStream_t stream) {
    const int*   glosses     = (const int*)d_in[0];
    const int*   words       = (const int*)d_in[1];
    const float* scores      = (const float*)d_in[2];
    const float* words_out   = (const float*)d_in[3];
    const int*   frames_len  = (const int*)d_in[4];
    const int*   glosses_len = (const int*)d_in[5];
    const int*   tag_ids     = (const int*)d_in[6];
    float* out = (float*)d_out;

    float* w       = (float*)d_ws;
    int*   counter = (int*)d_ws;   // w[0]
    float* loss_ws = w + 16;       // 64
    float* nll_ws  = w + 80;       // 1
    float* lp_ws   = w + 128;      // B*T*34 floats = 2.23 MB (16B-aligned)

    kA_booster<<<(B_ * T_) / 4, 256, 0, stream>>>(scores, tag_ids, glosses, lp_ws, counter);
    kB_ctc_nll_final<<<B_ + 1, 256, 0, stream>>>(lp_ws, glosses, frames_len, glosses_len,
                                                 words, words_out, loss_ws, nll_ws,
                                                 counter, out);
}

// Round 12
// 52.373 us; speedup vs baseline: 9.2332x; 1.0089x over previous
//
#include <hip/hip_runtime.h>

// Problem constants (from reference)
#define B_    64
#define T_    256
#define VG_   1232
#define S_    32
#define LW_   64
#define VW_   8000
#define NTAGS 8
#define NEG_  (-1e30f)
#define LP_STRIDE 34   // per (b,t): [0]=blank lp, [1..32]=gloss lp, [33]=pad
#define LOG2E 1.44269504088896340736f
#define LN2   0.69314718055994530942f

__device__ __forceinline__ float exp2g(float x) {
    float r; asm("v_exp_f32 %0, %1" : "=v"(r) : "v"(x)); return r;
}
__device__ __forceinline__ float log2g(float x) {
    float r; asm("v_log_f32 %0, %1" : "=v"(r) : "v"(x)); return r;
}
// Agent-scope store/load without cache-maintenance fences (sc1 path through
// the MALL coherence point; validated R9-R11: absmax 0).
__device__ __forceinline__ void st_agent(float* p, float v) {
    __hip_atomic_store(p, v, __ATOMIC_RELAXED, __HIP_MEMORY_SCOPE_AGENT);
}
__device__ __forceinline__ float ld_agent(const float* p) {
    return __hip_atomic_load(p, __ATOMIC_RELAXED, __HIP_MEMORY_SCOPE_AGENT);
}
// Whole-wave shift-up-by-1 via DPP WAVE_SHR1 (0x138): lane l gets src[l-1],
// lane 0 keeps `fill`. Pure VALU: no LDS round-trip, no lgkmcnt.
__device__ __forceinline__ float dpp_shr1(float x, float fill) {
    int r = __builtin_amdgcn_update_dpp(
        __builtin_bit_cast(int, fill), __builtin_bit_cast(int, x),
        0x138, 0xF, 0xF, false);
    return __builtin_bit_cast(float, r);
}
// One DPP row_shl<K> add step (ctrl must be a literal constant -> template).
template <int CTRL>
__device__ __forceinline__ float dpp_add(float x) {
    int s = __builtin_amdgcn_update_dpp(
        0, __builtin_bit_cast(int, x), CTRL, 0xF, 0xF, true);
    return x + __builtin_bit_cast(float, s);
}
// Wave sum to lane 0 (lanes 16/32/48 also hold it): DPP row_shl 1/2/4/8 on
// the VALU pipe + two cross-lane combines.
__device__ __forceinline__ float wave_sum_to0(float x) {
    x = dpp_add<0x101>(x);
    x = dpp_add<0x102>(x);
    x = dpp_add<0x104>(x);
    x = dpp_add<0x108>(x);
    x += __shfl_xor(x, 16, 64);
    x += __shfl_xor(x, 32, 64);
    return x;
}

// ---------------------------------------------------------------------------
// k0: per-tag counts -> 0.1*LOG2E/cnt (tiny, one block). Also zeroes kB's
// completion counter. (Separate kernel again: the R5 fold made EVERY kA block
// redo this with an LDS-atomic storm + barriers — the convoy was worse than
// the extra launch.)
// ---------------------------------------------------------------------------
__global__ void k0_counts(const int* __restrict__ tag_ids,
                          float* __restrict__ invcnt2, int* __restrict__ counter) {
    __shared__ int c[NTAGS];
    if (threadIdx.x == 0) *counter = 0;
    if (threadIdx.x < NTAGS) c[threadIdx.x] = 0;
    __syncthreads();
    for (int v = threadIdx.x; v < VG_; v += 256)
        atomicAdd(&c[tag_ids[v]], 1);   // integer atomics: deterministic
    __syncthreads();
    if (threadIdx.x < NTAGS)
        invcnt2[threadIdx.x] = (0.1f * LOG2E) / (float)c[threadIdx.x];
}

// ---------------------------------------------------------------------------
// kA: booster + max-free base-2 logsumexp + gather lp at {blank, glosses}.
// One wave per (b,t) row; 4 waves/block. BARRIER-FREE: tags loaded straight
// from global (int4, L2-resident), tm2 published into a wave-private LDS row
// (same-wave ds_write->ds_read is in-order; mechanism absmax-0 since R5).
// Waves never wait on each other -> stalls overlap across 32 waves/CU.
// Max-free LSE is safe: scores ~ N(0,1) (+0.1*tag_mean), sumexp <= ~5e5.
// lp stored in LOG2 domain for kB's scan.
// ---------------------------------------------------------------------------
__global__ __launch_bounds__(256) void kA_booster(
    const float* __restrict__ scores, const int* __restrict__ tag_ids,
    const int* __restrict__ glosses, const float* __restrict__ invcnt2,
    float* __restrict__ lp_ws)
{
    __shared__ float tm2L[4][NTAGS];   // wave-private rows; 128 B total
    const int tid  = threadIdx.x;
    const int lane = tid & 63;
    const int wv   = tid >> 6;
    const int row  = blockIdx.x * 4 + wv;      // [0, B*T)
    const int b    = row >> 8;                 // row / T_
    const float* srow = scores + (size_t)row * VG_;

    // Gather index (tiny load, issued early): lane 0 -> blank(0),
    // lanes 1..32 -> glosses[b, lane-1].
    const int gidx = (lane >= 1 && lane < 33) ? glosses[b * S_ + lane - 1] : 0;

    // Long-latency loads: scores (308 float4/row; 5/lane, last iter 52 lanes)
    // and tags (same shape, int4 from global — replaces LDS staging+atomics).
    float4 sv[5];
    int4   tv[5];
#pragma unroll
    for (int i = 0; i < 5; ++i) {
        const int idx = i * 64 + lane;
        const bool act = (i < 4) || (lane < 52);
        sv[i] = act ? ((const float4*)srow)[idx]  : make_float4(0.f, 0.f, 0.f, 0.f);
        tv[i] = act ? ((const int4*)tag_ids)[idx] : make_int4(0, 0, 0, 0);
    }
    // Pre-issue gather loads (overlap pass-1 compute).
    const float gval = srow[gidx];
    const int   gtag = tag_ids[gidx];

    // Pass 1: per-tag sums (inactive elements contribute 0 to tag 0: harmless)
    float sums[NTAGS];
#pragma unroll
    for (int n = 0; n < NTAGS; ++n) sums[n] = 0.f;
#pragma unroll
    for (int i = 0; i < 5; ++i) {
        const float xs[4] = {sv[i].x, sv[i].y, sv[i].z, sv[i].w};
        const int   ts[4] = {tv[i].x, tv[i].y, tv[i].z, tv[i].w};
#pragma unroll
        for (int j = 0; j < 4; ++j) {
#pragma unroll
            for (int n = 0; n < NTAGS; ++n)
                sums[n] += (ts[j] == n) ? xs[j] : 0.f;
        }
    }
#pragma unroll
    for (int n = 0; n < NTAGS; ++n) sums[n] = wave_sum_to0(sums[n]);

    // Lane 0 publishes tm2 into the wave-private LDS row (no barrier).
    if (lane == 0) {
#pragma unroll
        for (int n = 0; n < NTAGS; ++n)
            tm2L[wv][n] = sums[n] * invcnt2[n];   // = 0.1*mean*LOG2E
    }
    __builtin_amdgcn_sched_barrier(0);  // pin ds_write before the ds_reads

    // Pass 2: se = sum exp2(x*LOG2E + tm2[tag])  (max-free)
    float se = 0.f;
#pragma unroll
    for (int i = 0; i < 5; ++i) {
        const float xs[4] = {sv[i].x, sv[i].y, sv[i].z, sv[i].w};
        const int   ts[4] = {tv[i].x, tv[i].y, tv[i].z, tv[i].w};
        const bool act = (i < 4) || (lane < 52);
#pragma unroll
        for (int j = 0; j < 4; ++j) {
            const float e = exp2g(fmaf(xs[j], LOG2E, tm2L[wv][ts[j]]));
            se += act ? e : 0.f;
        }
    }
    se = wave_sum_to0(se);
    const float se0 = __builtin_bit_cast(
        float, __builtin_amdgcn_readfirstlane(__builtin_bit_cast(int, se)));
    const float lse2 = log2g(se0);             // log2(sum e^x)

    // lp2 = x*LOG2E + tm2 - lse2. Store in log2 domain.
    if (lane < 33) {
        const float v = fmaf(gval, LOG2E, tm2L[wv][gtag]) - lse2;
        lp_ws[(size_t)row * LP_STRIDE + lane] = v;
    }
}

// ---------------------------------------------------------------------------
// kB scan body, specialized on whether every step commits (Tlen == T).
// Neighbor exchange via DPP wave_shr1 (VALU) instead of ds_bpermute.
// ---------------------------------------------------------------------------
template <bool FULL>
__device__ __forceinline__ void scan_body(
    const float* __restrict__ tile, int lane, int off, bool ok2, int Tlen,
    float& alpha, float& a64)
{
    auto STEP = [&](int t, float lp, float lpB) {
        const float a1 = dpp_shr1(alpha, NEG_);          // lane0 -> NEG
        float a2 = dpp_shr1(a1, NEG_);                   // lanes0,1 -> NEG
        a2 = ok2 ? a2 : NEG_;
        const float m3 = fmaxf(alpha, fmaxf(a1, a2));    // v_max3
        const float e0 = exp2g(alpha - m3);
        const float e1 = exp2g(a1 - m3);
        const float e2 = exp2g(a2 - m3);
        const float nw = (m3 + lp) + log2g((e0 + e1) + e2);
        const float m2 = fmaxf(a64, alpha);              // a63 lane-local on 63
        const float n64 = (m2 + lpB) + log2g(exp2g(a64 - m2) + exp2g(alpha - m2));
        if (FULL || t < Tlen) { alpha = nw; a64 = n64; } // uniform
    };

    // 255 steps (t=1..255): 63 groups of 4 + tail of 3; next group's 8 LDS
    // reads issued one group ahead (ds latency hidden under the VALU chain).
    float cur[4], curB[4];
#pragma unroll
    for (int j = 0; j < 4; ++j) {
        cur[j]  = tile[(1 + j) * LP_STRIDE + off];
        curB[j] = tile[(1 + j) * LP_STRIDE];
    }
    int tbase = 1;
    for (int g = 0; g < 63; ++g) {
        float nxt[4], nxtB[4];
        const int tb2 = tbase + 4;             // last group reads pad row 256
#pragma unroll
        for (int j = 0; j < 4; ++j) {
            nxt[j]  = tile[(tb2 + j) * LP_STRIDE + off];
            nxtB[j] = tile[(tb2 + j) * LP_STRIDE];
        }
#pragma unroll
        for (int j = 0; j < 4; ++j) STEP(tbase + j, cur[j], curB[j]);
#pragma unroll
        for (int j = 0; j < 4; ++j) { cur[j] = nxt[j]; curB[j] = nxtB[j]; }
        tbase += 4;
    }
#pragma unroll
    for (int j = 0; j < 3; ++j) STEP(253 + j, cur[j], curB[j]);
}

// ---------------------------------------------------------------------------
// kB: blocks 0..63 = CTC alpha scan (lp tile staged to LDS, wave-0 scan).
// Block 64 = NLL gather. Completion is FENCE-FREE: loss/nll go out via sc1
// agent stores, each block drains vmcnt then does one device-scope atomicAdd;
// the 65th arrival reduces via sc1 loads. No __threadfence in this program.
// ---------------------------------------------------------------------------
__global__ __launch_bounds__(256) void kB_ctc_nll_final(
    const float* __restrict__ lp_ws, const int* __restrict__ glosses,
    const int* __restrict__ frames_len, const int* __restrict__ glosses_len,
    const int* __restrict__ words, const float* __restrict__ words_out,
    float* __restrict__ loss_ws, float* __restrict__ nll_ws,
    int* __restrict__ counter, float* __restrict__ out)
{
    __shared__ __align__(16) float tile[(T_ + 1) * LP_STRIDE];  // +pad row
    __shared__ float red[256];
    const int tid = threadIdx.x;

    if (blockIdx.x == B_) {
        // ---- NLL gather: 4032 scattered reads, fixed-order tree reduce ----
        float acc = 0.f;
        for (int idx = tid; idx < B_ * (LW_ - 1); idx += 256) {
            const int b = idx / (LW_ - 1);
            const int t = idx - b * (LW_ - 1);
            const int tgt = words[b * LW_ + t + 1];
            if (tgt != 0)
                acc -= words_out[((size_t)b * LW_ + t) * VW_ + tgt];
        }
        red[tid] = acc;
        __syncthreads();
        for (int s = 128; s > 0; s >>= 1) {
            if (tid < s) red[tid] += red[tid + s];
            __syncthreads();
        }
        if (tid == 0) st_agent(nll_ws, red[0]);          // sc1
    } else {
        const int b = blockIdx.x;
        // ---- stage lp tile: 8704 floats = 2176 float4, 256 threads ----
        {
            const float4* src4 = (const float4*)(lp_ws + (size_t)b * T_ * LP_STRIDE);
            float4* dst4 = (float4*)tile;
            float4 r[9];
#pragma unroll
            for (int i = 0; i < 9; ++i) {
                const int idx = i * 256 + tid;
                if (idx < 2176) r[i] = src4[idx];
            }
#pragma unroll
            for (int i = 0; i < 9; ++i) {
                const int idx = i * 256 + tid;
                if (idx < 2176) dst4[idx] = r[i];
            }
        }
        __syncthreads();
        if (tid >= 64) return;                 // scan is single-wave
        const int lane = tid;

        // ext[l]: even -> blank, odd -> glosses[b, l>>1]
        const bool odd  = (lane & 1) != 0;
        const int  sIdx = (lane - 1) >> 1;     // valid when odd
        bool ok2 = false;                      // may take the l-2 skip path
        if (odd && sIdx >= 1) {
            const int g  = glosses[b * S_ + sIdx];
            const int gp = glosses[b * S_ + sIdx - 1];
            ok2 = (g != gp) && (g != 0);
        }
        const int off = odd ? (1 + sIdx) : 0;  // column in the 34-wide row

        float alpha = NEG_;
        float a64   = NEG_;                    // state 64; valid on lane 63
        {
            const float lp00 = tile[off];
            if (lane <= 1) alpha = lp00;       // alpha0[0], alpha0[1]
        }
        const int Tlen = frames_len[b];

        if (Tlen == T_) scan_body<true >(tile, lane, off, ok2, Tlen, alpha, a64);
        else            scan_body<false>(tile, lane, off, ok2, Tlen, alpha, a64);

        const float a64v = __shfl(a64, 63, 64);
        const int i1 = 2 * glosses_len[b];     // in [2, 64]
        const int i0 = i1 - 1;
        const float A0 = __shfl(alpha, i0, 64);
        const float A1 = (i1 >= 64) ? a64v : __shfl(alpha, i1, 64);
        const float mm = fmaxf(A0, A1);
        float loss = -(mm + log2g(exp2g(A0 - mm) + exp2g(A1 - mm))) * LN2;
        if (loss > 1e29f) loss = 0.f;
        if (lane == 0) st_agent(&loss_ws[b], loss);      // sc1
    }

    // ---- completion, fence-free: drain own sc1 store, one RMW each ----
    asm volatile("s_waitcnt vmcnt(0)" ::: "memory");
    int old = 0;
    if (tid == 0) old = atomicAdd(counter, 1);
    if (tid < 64) {
        old = __shfl(old, 0, 64);
        if (old == B_) {                       // 65th arrival
            float v = ld_agent(&loss_ws[tid]); // sc1: MALL-coherent
#pragma unroll
            for (int o = 32; o >= 1; o >>= 1) v += __shfl_xor(v, o, 64);
            if (tid == 0) {
                const float trans = ld_agent(nll_ws);
                out[0] = v + trans;            // GLOSS_W = WORD_W = 1
                out[1] = v;
                out[2] = trans;
            }
        }
    }
}

// ---------------------------------------------------------------------------
extern "C" void kernel_launch(void* const* d_in, const int* in_sizes, int n_in,
                              void* d_out, int out_size, void* d_ws, size_t ws_size,
                              hipStream_t stream) {
    const int*   glosses     = (const int*)d_in[0];
    const int*   words       = (const int*)d_in[1];
    const float* scores      = (const float*)d_in[2];
    const float* words_out   = (const float*)d_in[3];
    const int*   frames_len  = (const int*)d_in[4];
    const int*   glosses_len = (const int*)d_in[5];
    const int*   tag_ids     = (const int*)d_in[6];
    float* out = (float*)d_out;

    float* w       = (float*)d_ws;
    int*   counter = (int*)d_ws;   // w[0]
    float* invcnt2 = w + 8;        // 8 floats: 0.1*LOG2E/cnt[n]
    float* loss_ws = w + 16;       // 64
    float* nll_ws  = w + 80;       // 1
    float* lp_ws   = w + 128;      // B*T*34 floats = 2.23 MB (16B-aligned)

    k0_counts<<<1, 256, 0, stream>>>(tag_ids, invcnt2, counter);
    kA_booster<<<(B_ * T_) / 4, 256, 0, stream>>>(scores, tag_ids, glosses,
                                                  invcnt2, lp_ws);
    kB_ctc_nll_final<<<B_ + 1, 256, 0, stream>>>(lp_ws, glosses, frames_len,
                                                 glosses_len, words, words_out,
                                                 loss_ws, nll_ws, counter, out);
}